// Round 3
// baseline (1980.730 us; speedup 1.0000x reference)
//
#include <hip/hip_runtime.h>

#define N_ATOMS 200000
#define N_BONDS 400000
#define MAX_NEI 10
#define N_MOLS  8000
#define AFD 87
#define BFD 6
#define H 64

// ---------------------------------------------------------------------------
// T: M1 = W_bemb @ V1 ; M2 = W_bemb @ W1   (both [6][64], one block)
// ---------------------------------------------------------------------------
__global__ __launch_bounds__(256) void k_tiny(
    const float* __restrict__ Wb, const float* __restrict__ V1,
    const float* __restrict__ W1, float* __restrict__ M1, float* __restrict__ M2)
{
    int t = threadIdx.x;
    for (int idx = t; idx < BFD * H; idx += 256) {
        int k = idx >> 6, h = idx & 63;
        float a1 = 0.f, a2 = 0.f;
        for (int j = 0; j < H; ++j) {
            float w = Wb[k * H + j];
            a1 = fmaf(w, V1[j * H + h], a1);
            a2 = fmaf(w, W1[j * H + h], a2);
        }
        M1[idx] = a1;
        M2[idx] = a2;
    }
}

// ---------------------------------------------------------------------------
// A: h_atom = atom_feat @ W_emb ; g_atom0 = h_atom @ V2   (fused, 4 rows/block)
// ---------------------------------------------------------------------------
__global__ __launch_bounds__(256) void k_atom_emb(
    const float* __restrict__ af, const float* __restrict__ Wemb,
    const float* __restrict__ V2, float* __restrict__ h_atom,
    float* __restrict__ g_atom)
{
    __shared__ float sW[AFD * H];
    __shared__ float sV[H * H];
    __shared__ float srow[4][AFD];
    __shared__ float sh[4][H];
    int tid = threadIdx.x;
    for (int t = tid; t < AFD * H; t += 256) sW[t] = Wemb[t];
    for (int t = tid; t < H * H; t += 256) sV[t] = V2[t];
    int r = tid >> 6, h = tid & 63;
    int row = blockIdx.x * 4 + r;                 // N_ATOMS % 4 == 0, exact grid
    for (int k = h; k < AFD; k += 64) srow[r][k] = af[row * AFD + k];
    __syncthreads();
    float acc = 0.f;
#pragma unroll
    for (int k = 0; k < AFD; ++k) acc = fmaf(srow[r][k], sW[k * H + h], acc);
    h_atom[row * H + h] = acc;
    sh[r][h] = acc;
    __syncthreads();
    float g = 0.f;
#pragma unroll
    for (int k = 0; k < H; ++k) g = fmaf(sh[r][k], sV[k * H + h], g);
    g_atom[row * H + h] = g;
}

// ---------------------------------------------------------------------------
// E: h_new = relu(h_old@U1 + nei@U2); extra = h_new @ Mx   (in-place safe:
//    each thread reads only its own row of h; gathers read g_atom/bond_feat)
//    nei[i,h] = sum_k relu( (bond_feat[bg[i,k]] @ M1)[h] + g_atom[ag[i,k],h] )
// ---------------------------------------------------------------------------
__global__ __launch_bounds__(256) void k_update(
    const float* __restrict__ h_in,
    const float* __restrict__ g_atom,
    const float* __restrict__ bf, const float* __restrict__ M1,
    const int* __restrict__ ag, const int* __restrict__ bg,
    const float* __restrict__ U1, const float* __restrict__ U2,
    const float* __restrict__ Mx,
    float* __restrict__ h_out, float* __restrict__ extra_out)
{
    __shared__ float sU1[H * H];
    __shared__ float sU2[H * H];
    __shared__ float sMx[H * H];
    __shared__ float srow[4][H];
    __shared__ float snei[4][H];
    __shared__ float snew[4][H];
    int tid = threadIdx.x;
    for (int t = tid; t < H * H; t += 256) { sU1[t] = U1[t]; sU2[t] = U2[t]; sMx[t] = Mx[t]; }
    int r = tid >> 6, h = tid & 63;       // each row group == one full wave
    int row = blockIdx.x * 4 + r;
    float m1c[BFD];
#pragma unroll
    for (int j = 0; j < BFD; ++j) m1c[j] = M1[j * H + h];   // M1 column h
    srow[r][h] = h_in[row * H + h];
    float acc = 0.f;
#pragma unroll
    for (int k = 0; k < MAX_NEI; ++k) {
        int ia = ag[row * MAX_NEI + k];
        int ib = bg[row * MAX_NEI + k];
        float bv = (h < BFD) ? bf[ib * BFD + h] : 0.f;      // 6 lanes load 24 B
        float gb = 0.f;
#pragma unroll
        for (int j = 0; j < BFD; ++j) gb = fmaf(__shfl(bv, j, 64), m1c[j], gb);
        float v = gb + g_atom[ia * H + h];
        acc += fmaxf(v, 0.f);
    }
    snei[r][h] = acc;
    __syncthreads();
    float o = 0.f;
#pragma unroll
    for (int k = 0; k < H; ++k) o = fmaf(srow[r][k], sU1[k * H + h], o);
#pragma unroll
    for (int k = 0; k < H; ++k) o = fmaf(snei[r][k], sU2[k * H + h], o);
    o = fmaxf(o, 0.f);
    h_out[row * H + h] = o;
    snew[r][h] = o;
    __syncthreads();
    float g = 0.f;
#pragma unroll
    for (int k = 0; k < H; ++k) g = fmaf(snew[r][k], sMx[k * H + h], g);
    extra_out[row * H + h] = g;
}

// ---------------------------------------------------------------------------
// F: c_atom[i,h] = (h2@W0)[i,h] *
//                  sum_k p_atom[ag[i,k],h] * (bond_feat[bg[i,k]] @ M2)[h]
// ---------------------------------------------------------------------------
__global__ __launch_bounds__(256) void k_catom(
    const float* __restrict__ h2,
    const float* __restrict__ p_atom,
    const float* __restrict__ bf, const float* __restrict__ M2,
    const int* __restrict__ ag, const int* __restrict__ bg,
    const float* __restrict__ W0, float* __restrict__ c_atom)
{
    __shared__ float sW[H * H];
    __shared__ float srow[4][H];
    int tid = threadIdx.x;
    for (int t = tid; t < H * H; t += 256) sW[t] = W0[t];
    int r = tid >> 6, h = tid & 63;
    int row = blockIdx.x * 4 + r;
    float m2c[BFD];
#pragma unroll
    for (int j = 0; j < BFD; ++j) m2c[j] = M2[j * H + h];
    srow[r][h] = h2[row * H + h];
    float s = 0.f;
#pragma unroll
    for (int k = 0; k < MAX_NEI; ++k) {
        int ia = ag[row * MAX_NEI + k];
        int ib = bg[row * MAX_NEI + k];
        float bv = (h < BFD) ? bf[ib * BFD + h] : 0.f;
        float pb = 0.f;
#pragma unroll
        for (int j = 0; j < BFD; ++j) pb = fmaf(__shfl(bv, j, 64), m2c[j], pb);
        s = fmaf(p_atom[ia * H + h], pb, s);
    }
    __syncthreads();
    float f = 0.f;
#pragma unroll
    for (int k = 0; k < H; ++k) f = fmaf(srow[r][k], sW[k * H + h], f);
    c_atom[row * H + h] = f * s;
}

// ---------------------------------------------------------------------------
// H: c_mol[m] = sum over contiguous atom slice (mol_ids sorted, binary search)
// ---------------------------------------------------------------------------
__global__ void k_segsum(
    const float* __restrict__ c_atom, const int* __restrict__ mol_ids,
    float* __restrict__ c_mol)
{
    int m = blockIdx.x;
    int h = threadIdx.x;           // 64 threads
    int lo = 0, hi = N_ATOMS;
    while (lo < hi) { int mid = (lo + hi) >> 1; if (mol_ids[mid] < m) lo = mid + 1; else hi = mid; }
    int start = lo;
    hi = N_ATOMS;
    while (lo < hi) { int mid = (lo + hi) >> 1; if (mol_ids[mid] < m + 1) lo = mid + 1; else hi = mid; }
    int end = lo;
    float acc = 0.f;
    for (int a = start; a < end; ++a) acc += c_atom[a * H + h];
    c_mol[m * H + h] = acc;
}

extern "C" void kernel_launch(void* const* d_in, const int* in_sizes, int n_in,
                              void* d_out, int out_size, void* d_ws, size_t ws_size,
                              hipStream_t stream)
{
    const float* atom_feat = (const float*)d_in[0];
    const float* bond_feat = (const float*)d_in[1];
    const int*   ag        = (const int*)d_in[2];
    const int*   bg        = (const int*)d_in[3];
    const int*   mol_ids   = (const int*)d_in[4];
    const float* W_aemb    = (const float*)d_in[5];
    const float* W_bemb    = (const float*)d_in[6];
    const float* U1        = (const float*)d_in[7];
    const float* U2        = (const float*)d_in[8];
    const float* V         = (const float*)d_in[9];
    const float* W0        = (const float*)d_in[10];
    const float* W1        = (const float*)d_in[11];
    const float* W2        = (const float*)d_in[12];

    float* out    = (float*)d_out;
    float* c_mol  = out;
    float* c_atom = out + (size_t)N_MOLS * H;   // also used as g_atom scratch (gA1)

    // workspace: 2 atom-sized buffers + 2 tiny matrices = 102.4 MB + 3 KB
    float* hA  = (float*)d_ws;                  // [N_ATOMS*H] h_atom (in-place)
    float* gA0 = hA  + (size_t)N_ATOMS * H;     // [N_ATOMS*H] g_atom ping
    float* M1  = gA0 + (size_t)N_ATOMS * H;     // [6*64] W_bemb@V1
    float* M2  = M1  + BFD * H;                 // [6*64] W_bemb@W1
    float* gA1 = c_atom;                        // pong lives in d_out (dead by k_catom)

    const float* V1 = V;            // V rows 0..63   (h_bond_nei part of concat)
    const float* V2 = V + H * H;    // V rows 64..127 (h_atom_nei part)

    // tiny bond-side precompute: M1 = Wb@V1, M2 = Wb@W1
    k_tiny<<<1, 256, 0, stream>>>(W_bemb, V1, W1, M1, M2);

    // h0 = af@Waemb ; g_atom0 = h0@V2
    k_atom_emb<<<N_ATOMS / 4, 256, 0, stream>>>(atom_feat, W_aemb, V2, hA, gA0);

    // iter 0: h1 = relu(h0@U1 + nei@U2); gA1 = h1@V2
    k_update<<<N_ATOMS / 4, 256, 0, stream>>>(hA, gA0, bond_feat, M1, ag, bg,
                                              U1, U2, V2, hA, gA1);
    // iter 1: h2 = relu(h1@U1 + nei@U2); gA0 = p_atom = h2@W2
    k_update<<<N_ATOMS / 4, 256, 0, stream>>>(hA, gA1, bond_feat, M1, ag, bg,
                                              U1, U2, W2, hA, gA0);

    // iter 2 (last): c_atom = (h2@W0) * sum_k p_atom[ag]*(bf[bg]@M2)
    // (final h-update is dead code; writes over gA1's region, which is dead)
    k_catom<<<N_ATOMS / 4, 256, 0, stream>>>(hA, gA0, bond_feat, M2, ag, bg,
                                             W0, c_atom);

    // scope pooling
    k_segsum<<<N_MOLS, 64, 0, stream>>>(c_atom, mol_ids, c_mol);
}

// Round 4
// 798.727 us; speedup vs baseline: 2.4799x; 2.4799x over previous
//
#include <hip/hip_runtime.h>

#define N_ATOMS 200000
#define N_BONDS 400000
#define MAX_NEI 10
#define N_MOLS  8000
#define AFD 87
#define BFD 6
#define H 64
#define WPB 16          // waves per block (1024 threads)
#define RPW 4           // rows per wave
#define RPB (WPB*RPW)   // 64 rows per block

// ---------------------------------------------------------------------------
// T: M1 = W_bemb @ V1 ; M2 = W_bemb @ W1   (both [6][64], one block)
// ---------------------------------------------------------------------------
__global__ __launch_bounds__(256) void k_tiny(
    const float* __restrict__ Wb, const float* __restrict__ V1,
    const float* __restrict__ W1, float* __restrict__ M1, float* __restrict__ M2)
{
    int t = threadIdx.x;
    for (int idx = t; idx < BFD * H; idx += 256) {
        int k = idx >> 6, h = idx & 63;
        float a1 = 0.f, a2 = 0.f;
        for (int j = 0; j < H; ++j) {
            float w = Wb[k * H + j];
            a1 = fmaf(w, V1[j * H + h], a1);
            a2 = fmaf(w, W1[j * H + h], a2);
        }
        M1[idx] = a1;
        M2[idx] = a2;
    }
}

// ---------------------------------------------------------------------------
// A: h_atom = af@Wemb ; g_atom0 = h_atom@V2.  4 rows/wave, transposed staging.
// LDS: 22272 + 16384 + 22272 = 60928 B -> 2 blocks/CU.
// ---------------------------------------------------------------------------
__global__ __launch_bounds__(1024, 8) void k_atom_emb(
    const float* __restrict__ af, const float* __restrict__ Wemb,
    const float* __restrict__ V2, float* __restrict__ h_atom,
    float* __restrict__ g_atom)
{
    __shared__ float sW[AFD * H];          // 22272 B
    __shared__ float sV[H * H];            // 16384 B
    __shared__ float sT[WPB * AFD * 4];    // 22272 B (per-wave transposed rows)
    int tid = threadIdx.x;
    for (int t = tid; t < AFD * H / 4; t += 1024)
        ((float4*)sW)[t] = ((const float4*)Wemb)[t];
    ((float4*)sV)[tid] = ((const float4*)V2)[tid];      // 1024 float4 exactly
    int w = tid >> 6, h = tid & 63;
    int row0 = __builtin_amdgcn_readfirstlane((int)(blockIdx.x * RPB + w * RPW));
    float* myT = sT + w * (AFD * 4);
    for (int c = h; c < AFD; c += 64) {
#pragma unroll
        for (int i = 0; i < RPW; ++i)
            myT[c * 4 + i] = af[(size_t)(row0 + i) * AFD + c];
    }
    __syncthreads();
    const float4* myTv = (const float4*)myT;
    float a0 = 0.f, a1 = 0.f, a2 = 0.f, a3 = 0.f;
#pragma unroll 4
    for (int k = 0; k < AFD; ++k) {
        float u = sW[k * H + h];
        float4 s = myTv[k];
        a0 = fmaf(s.x, u, a0); a1 = fmaf(s.y, u, a1);
        a2 = fmaf(s.z, u, a2); a3 = fmaf(s.w, u, a3);
    }
    h_atom[(size_t)(row0 + 0) * H + h] = a0;
    h_atom[(size_t)(row0 + 1) * H + h] = a1;
    h_atom[(size_t)(row0 + 2) * H + h] = a2;
    h_atom[(size_t)(row0 + 3) * H + h] = a3;
    ((float4*)myT)[h] = make_float4(a0, a1, a2, a3);   // reuse as transposed h
    float g0 = 0.f, g1 = 0.f, g2 = 0.f, g3 = 0.f;
#pragma unroll 4
    for (int k = 0; k < H; ++k) {
        float v = sV[k * H + h];
        float4 s = myTv[k];
        g0 = fmaf(s.x, v, g0); g1 = fmaf(s.y, v, g1);
        g2 = fmaf(s.z, v, g2); g3 = fmaf(s.w, v, g3);
    }
    g_atom[(size_t)(row0 + 0) * H + h] = g0;
    g_atom[(size_t)(row0 + 1) * H + h] = g1;
    g_atom[(size_t)(row0 + 2) * H + h] = g2;
    g_atom[(size_t)(row0 + 3) * H + h] = g3;
}

// ---------------------------------------------------------------------------
// E: h_new = relu(h@U1 + nei@U2); extra = h_new@Mx.  4 rows/wave.
// nei[i,h] = sum_k relu( (bf[bg[i,k]]@M1)[h] + g_atom[ag[i,k],h] )
// LDS: 16K(U1)+16K(U2)+16K(sRow)+16K(sNei) = 65536 B exactly -> 2 blocks/CU.
// Mx is read through L1 (16 KB, resident).
// ---------------------------------------------------------------------------
#define GATHER_NEI(i, OUT) do {                                              \
    const int* agp = ag + (size_t)(row0 + (i)) * MAX_NEI;                    \
    const int* bgp = bg + (size_t)(row0 + (i)) * MAX_NEI;                    \
    float a = 0.f;                                                           \
    _Pragma("unroll")                                                        \
    for (int k = 0; k < MAX_NEI; ++k) {                                      \
        int ia = agp[k];                                                     \
        int ib = bgp[k];                                                     \
        float ga = g_atom[(size_t)ia * H + h];                               \
        const float* bp = bf + (size_t)ib * BFD;                             \
        float gb = 0.f;                                                      \
        _Pragma("unroll")                                                    \
        for (int j = 0; j < BFD; ++j) gb = fmaf(bp[j], m1c[j], gb);          \
        a += fmaxf(gb + ga, 0.f);                                            \
    }                                                                        \
    OUT = a;                                                                 \
} while (0)

__global__ __launch_bounds__(1024, 8) void k_update(
    const float* __restrict__ h_in, const float* __restrict__ g_atom,
    const float* __restrict__ bf, const float* __restrict__ M1,
    const int* __restrict__ ag, const int* __restrict__ bg,
    const float* __restrict__ U1, const float* __restrict__ U2,
    const float* __restrict__ Mx,
    float* __restrict__ h_out, float* __restrict__ extra_out)
{
    __shared__ float sU1[H * H];        // 16 KB
    __shared__ float sU2[H * H];        // 16 KB
    __shared__ float4 sRow[WPB][H];     // 16 KB
    __shared__ float4 sNei[WPB][H];     // 16 KB
    int tid = threadIdx.x;
    ((float4*)sU1)[tid] = ((const float4*)U1)[tid];
    ((float4*)sU2)[tid] = ((const float4*)U2)[tid];
    int w = tid >> 6, h = tid & 63;
    int row0 = __builtin_amdgcn_readfirstlane((int)(blockIdx.x * RPB + w * RPW));
    float m1c[BFD];
#pragma unroll
    for (int j = 0; j < BFD; ++j) m1c[j] = M1[j * H + h];
    float x0 = h_in[(size_t)(row0 + 0) * H + h];
    float x1 = h_in[(size_t)(row0 + 1) * H + h];
    float x2 = h_in[(size_t)(row0 + 2) * H + h];
    float x3 = h_in[(size_t)(row0 + 3) * H + h];
    sRow[w][h] = make_float4(x0, x1, x2, x3);
    float n0, n1, n2, n3;
    GATHER_NEI(0, n0);
    GATHER_NEI(1, n1);
    GATHER_NEI(2, n2);
    GATHER_NEI(3, n3);
    sNei[w][h] = make_float4(n0, n1, n2, n3);
    __syncthreads();
    float o0 = 0.f, o1 = 0.f, o2 = 0.f, o3 = 0.f;
#pragma unroll 4
    for (int k = 0; k < H; ++k) {
        float u = sU1[k * H + h];
        float4 s = sRow[w][k];
        o0 = fmaf(s.x, u, o0); o1 = fmaf(s.y, u, o1);
        o2 = fmaf(s.z, u, o2); o3 = fmaf(s.w, u, o3);
    }
#pragma unroll 4
    for (int k = 0; k < H; ++k) {
        float u = sU2[k * H + h];
        float4 s = sNei[w][k];
        o0 = fmaf(s.x, u, o0); o1 = fmaf(s.y, u, o1);
        o2 = fmaf(s.z, u, o2); o3 = fmaf(s.w, u, o3);
    }
    o0 = fmaxf(o0, 0.f); o1 = fmaxf(o1, 0.f);
    o2 = fmaxf(o2, 0.f); o3 = fmaxf(o3, 0.f);
    h_out[(size_t)(row0 + 0) * H + h] = o0;
    h_out[(size_t)(row0 + 1) * H + h] = o1;
    h_out[(size_t)(row0 + 2) * H + h] = o2;
    h_out[(size_t)(row0 + 3) * H + h] = o3;
    sRow[w][h] = make_float4(o0, o1, o2, o3);          // reuse as snew (own wave)
    float g0 = 0.f, g1 = 0.f, g2 = 0.f, g3 = 0.f;
#pragma unroll 4
    for (int k = 0; k < H; ++k) {
        float u = Mx[k * H + h];                       // L1-resident 16 KB
        float4 s = sRow[w][k];
        g0 = fmaf(s.x, u, g0); g1 = fmaf(s.y, u, g1);
        g2 = fmaf(s.z, u, g2); g3 = fmaf(s.w, u, g3);
    }
    extra_out[(size_t)(row0 + 0) * H + h] = g0;
    extra_out[(size_t)(row0 + 1) * H + h] = g1;
    extra_out[(size_t)(row0 + 2) * H + h] = g2;
    extra_out[(size_t)(row0 + 3) * H + h] = g3;
}

// ---------------------------------------------------------------------------
// F: c_atom[i,h] = (h2@W0)[i,h] * sum_k p_atom[ag[i,k],h]*(bf[bg[i,k]]@M2)[h]
// ---------------------------------------------------------------------------
__global__ __launch_bounds__(1024, 8) void k_catom(
    const float* __restrict__ h2, const float* __restrict__ p_atom,
    const float* __restrict__ bf, const float* __restrict__ M2,
    const int* __restrict__ ag, const int* __restrict__ bg,
    const float* __restrict__ W0, float* __restrict__ c_atom)
{
    __shared__ float sW[H * H];         // 16 KB
    __shared__ float4 sRow[WPB][H];     // 16 KB
    int tid = threadIdx.x;
    ((float4*)sW)[tid] = ((const float4*)W0)[tid];
    int w = tid >> 6, h = tid & 63;
    int row0 = __builtin_amdgcn_readfirstlane((int)(blockIdx.x * RPB + w * RPW));
    float m2c[BFD];
#pragma unroll
    for (int j = 0; j < BFD; ++j) m2c[j] = M2[j * H + h];
    float x0 = h2[(size_t)(row0 + 0) * H + h];
    float x1 = h2[(size_t)(row0 + 1) * H + h];
    float x2 = h2[(size_t)(row0 + 2) * H + h];
    float x3 = h2[(size_t)(row0 + 3) * H + h];
    sRow[w][h] = make_float4(x0, x1, x2, x3);
    float s0, s1, s2, s3;
#define GATHER_PROD(i, OUT) do {                                             \
    const int* agp = ag + (size_t)(row0 + (i)) * MAX_NEI;                    \
    const int* bgp = bg + (size_t)(row0 + (i)) * MAX_NEI;                    \
    float a = 0.f;                                                           \
    _Pragma("unroll")                                                        \
    for (int k = 0; k < MAX_NEI; ++k) {                                      \
        int ia = agp[k];                                                     \
        int ib = bgp[k];                                                     \
        float pa = p_atom[(size_t)ia * H + h];                               \
        const float* bp = bf + (size_t)ib * BFD;                             \
        float pb = 0.f;                                                      \
        _Pragma("unroll")                                                    \
        for (int j = 0; j < BFD; ++j) pb = fmaf(bp[j], m2c[j], pb);          \
        a = fmaf(pa, pb, a);                                                 \
    }                                                                        \
    OUT = a;                                                                 \
} while (0)
    GATHER_PROD(0, s0);
    GATHER_PROD(1, s1);
    GATHER_PROD(2, s2);
    GATHER_PROD(3, s3);
    __syncthreads();
    float f0 = 0.f, f1 = 0.f, f2 = 0.f, f3 = 0.f;
#pragma unroll 4
    for (int k = 0; k < H; ++k) {
        float u = sW[k * H + h];
        float4 s = sRow[w][k];
        f0 = fmaf(s.x, u, f0); f1 = fmaf(s.y, u, f1);
        f2 = fmaf(s.z, u, f2); f3 = fmaf(s.w, u, f3);
    }
    c_atom[(size_t)(row0 + 0) * H + h] = f0 * s0;
    c_atom[(size_t)(row0 + 1) * H + h] = f1 * s1;
    c_atom[(size_t)(row0 + 2) * H + h] = f2 * s2;
    c_atom[(size_t)(row0 + 3) * H + h] = f3 * s3;
}

// ---------------------------------------------------------------------------
// H: c_mol[m] = sum over contiguous atom slice (mol_ids sorted, binary search)
// ---------------------------------------------------------------------------
__global__ void k_segsum(
    const float* __restrict__ c_atom, const int* __restrict__ mol_ids,
    float* __restrict__ c_mol)
{
    int m = blockIdx.x;
    int h = threadIdx.x;           // 64 threads
    int lo = 0, hi = N_ATOMS;
    while (lo < hi) { int mid = (lo + hi) >> 1; if (mol_ids[mid] < m) lo = mid + 1; else hi = mid; }
    int start = lo;
    hi = N_ATOMS;
    while (lo < hi) { int mid = (lo + hi) >> 1; if (mol_ids[mid] < m + 1) lo = mid + 1; else hi = mid; }
    int end = lo;
    float acc = 0.f;
    for (int a = start; a < end; ++a) acc += c_atom[a * H + h];
    c_mol[m * H + h] = acc;
}

extern "C" void kernel_launch(void* const* d_in, const int* in_sizes, int n_in,
                              void* d_out, int out_size, void* d_ws, size_t ws_size,
                              hipStream_t stream)
{
    const float* atom_feat = (const float*)d_in[0];
    const float* bond_feat = (const float*)d_in[1];
    const int*   ag        = (const int*)d_in[2];
    const int*   bg        = (const int*)d_in[3];
    const int*   mol_ids   = (const int*)d_in[4];
    const float* W_aemb    = (const float*)d_in[5];
    const float* W_bemb    = (const float*)d_in[6];
    const float* U1        = (const float*)d_in[7];
    const float* U2        = (const float*)d_in[8];
    const float* V         = (const float*)d_in[9];
    const float* W0        = (const float*)d_in[10];
    const float* W1        = (const float*)d_in[11];
    const float* W2        = (const float*)d_in[12];

    float* out    = (float*)d_out;
    float* c_mol  = out;
    float* c_atom = out + (size_t)N_MOLS * H;   // also g_atom pong scratch

    float* hA  = (float*)d_ws;                  // [N_ATOMS*H] h_atom (in-place)
    float* gA0 = hA  + (size_t)N_ATOMS * H;     // [N_ATOMS*H] g_atom ping
    float* M1  = gA0 + (size_t)N_ATOMS * H;     // [6*64]
    float* M2  = M1  + BFD * H;                 // [6*64]
    float* gA1 = c_atom;                        // pong in d_out (dead by k_catom)

    const float* V1 = V;            // V rows 0..63   (h_bond_nei part)
    const float* V2 = V + H * H;    // V rows 64..127 (h_atom_nei part)

    k_tiny<<<1, 256, 0, stream>>>(W_bemb, V1, W1, M1, M2);

    k_atom_emb<<<N_ATOMS / RPB, 1024, 0, stream>>>(atom_feat, W_aemb, V2, hA, gA0);

    // iter 0: h1 = relu(h0@U1 + nei@U2); gA1 = h1@V2
    k_update<<<N_ATOMS / RPB, 1024, 0, stream>>>(hA, gA0, bond_feat, M1, ag, bg,
                                                 U1, U2, V2, hA, gA1);
    // iter 1: h2 = relu(h1@U1 + nei@U2); gA0 = p_atom = h2@W2
    k_update<<<N_ATOMS / RPB, 1024, 0, stream>>>(hA, gA1, bond_feat, M1, ag, bg,
                                                 U1, U2, W2, hA, gA0);

    // iter 2 (last): c_atom = (h2@W0) * sum_k p_atom[ag]*(bf[bg]@M2)
    k_catom<<<N_ATOMS / RPB, 1024, 0, stream>>>(hA, gA0, bond_feat, M2, ag, bg,
                                                W0, c_atom);

    k_segsum<<<N_MOLS, 64, 0, stream>>>(c_atom, mol_ids, c_mol);
}